// Round 7
// baseline (1951.504 us; speedup 1.0000x reference)
//
#include <hip/hip_runtime.h>
#include <hip/hip_bf16.h>
#include <stdint.h>

// LSTM forward, B=64 T=512 D=512 H=512, return_sequences.
// v7 = v6 (MALL-scope flag-in-data stamping, proven) with latency trims:
//  - stores never waited (counted vmcnt: entry vmcnt(2), poll-wait vmcnt(4))
//  - x loads plain (L2-cached, no nt), double-buffered regs, 2x-unrolled loop
//  - 8-word stamp check (1 per dwordx4; producer line-atomic wave stores)
//  - v_perm_b32 unpack; EX double-buffered -> one barrier/step
// h published per-thread as u32 = bf16hi<<16 | bf16lo&0xFFF0 | stamp4.

#define Bdim 64
#define Tdim 512
#define Ddim 512
#define Hdim 512
#define G4H  2048
#define NG 4
#define NS 32
#define BH (Bdim * Hdim)  // u32 elems per parity plane

typedef __bf16 bf16_t;
typedef __bf16 bf16x8 __attribute__((ext_vector_type(8)));
typedef float  f32x4  __attribute__((ext_vector_type(4)));
typedef uint32_t u32x4 __attribute__((ext_vector_type(4)));
union pv128 { u32x4 u; f32x4 f; bf16x8 h; };
union bu16 { bf16_t b; unsigned short u; };

__device__ __forceinline__ float sigmoid_f(float x) {
  return 1.0f / (1.0f + __expf(-x));
}
__device__ __forceinline__ float tanh_f(float x) {
  return 1.0f - 2.0f / (__expf(2.0f * x) + 1.0f);  // stable both tails
}

// src [512][2048] fp32  ->  dst [2048][512] bf16 (transposed)
__global__ void transpose_bf16_512x2048(const float* __restrict__ src,
                                        bf16_t* __restrict__ dst) {
  __shared__ bf16_t tile[64][72];
  int c0 = blockIdx.x * 64;
  int r0 = blockIdx.y * 64;
  int tx = threadIdx.x & 63;
  int ty = threadIdx.x >> 6;
#pragma unroll
  for (int i = 0; i < 64; i += 4)
    tile[ty + i][tx] = (bf16_t)src[(size_t)(r0 + ty + i) * G4H + c0 + tx];
  __syncthreads();
#pragma unroll
  for (int i = 0; i < 64; i += 4)
    dst[(size_t)(c0 + ty + i) * Ddim + r0 + tx] = tile[tx][ty + i];
}

// fp32 -> bf16 elementwise (x pre-conversion), 8 elems/thread
__global__ void cast_bf16(const float* __restrict__ in, bf16_t* __restrict__ out) {
  size_t i = ((size_t)blockIdx.x * blockDim.x + threadIdx.x) * 8;
  f32x4 a = *(const f32x4*)(in + i);
  f32x4 b = *(const f32x4*)(in + i + 4);
  bf16x8 v;
#pragma unroll
  for (int j = 0; j < 4; ++j) { v[j] = (bf16_t)a[j]; v[j + 4] = (bf16_t)b[j]; }
  *(bf16x8*)(out + i) = v;
}

#define MFMA16(A, B, C) __builtin_amdgcn_mfma_f32_16x16x32_bf16(A, B, C, 0, 0, 0)

// 8 stamped h loads (2 per k-chunk), MALL-direct
#define ISSUE_POLL()                                                         \
  asm volatile(                                                              \
      "global_load_dwordx4 %0, %8, off sc0 sc1\n\t"                          \
      "global_load_dwordx4 %1, %8, off offset:16 sc0 sc1\n\t"                \
      "global_load_dwordx4 %2, %8, off offset:128 sc0 sc1\n\t"               \
      "global_load_dwordx4 %3, %8, off offset:144 sc0 sc1\n\t"               \
      "global_load_dwordx4 %4, %8, off offset:256 sc0 sc1\n\t"               \
      "global_load_dwordx4 %5, %8, off offset:272 sc0 sc1\n\t"               \
      "global_load_dwordx4 %6, %8, off offset:384 sc0 sc1\n\t"               \
      "global_load_dwordx4 %7, %8, off offset:400 sc0 sc1"                   \
      : "=v"(p0.f), "=v"(p1.f), "=v"(p2.f), "=v"(p3.f), "=v"(p4.f),          \
        "=v"(p5.f), "=v"(p6.f), "=v"(p7.f)                                   \
      : "v"(hb)                                                              \
      : "memory")

// one stamp check per 16B load (producer wave-store is line-atomic)
#define CHECK8()                                                             \
  do {                                                                       \
    bad = (p0.u[0] ^ st) & 15u;                                              \
    bad |= (p1.u[0] ^ st) & 15u;                                             \
    bad |= (p2.u[0] ^ st) & 15u;                                             \
    bad |= (p3.u[0] ^ st) & 15u;                                             \
    bad |= (p4.u[0] ^ st) & 15u;                                             \
    bad |= (p5.u[0] ^ st) & 15u;                                             \
    bad |= (p6.u[0] ^ st) & 15u;                                             \
    bad |= (p7.u[0] ^ st) & 15u;                                             \
  } while (0)

// unpack chunk c (8 u32 -> hi/lo bf16x8 via v_perm) and run 8 MFMAs
#define HU(PA, PB, c)                                                        \
  do {                                                                       \
    pv128 hi_, lo_;                                                          \
    hi_.u[0] = __builtin_amdgcn_perm(PA.u[1], PA.u[0], 0x07060302u);         \
    hi_.u[1] = __builtin_amdgcn_perm(PA.u[3], PA.u[2], 0x07060302u);         \
    hi_.u[2] = __builtin_amdgcn_perm(PB.u[1], PB.u[0], 0x07060302u);         \
    hi_.u[3] = __builtin_amdgcn_perm(PB.u[3], PB.u[2], 0x07060302u);         \
    lo_.u[0] = __builtin_amdgcn_perm(PA.u[1], PA.u[0], 0x05040100u) & 0xFFF0FFF0u; \
    lo_.u[1] = __builtin_amdgcn_perm(PA.u[3], PA.u[2], 0x05040100u) & 0xFFF0FFF0u; \
    lo_.u[2] = __builtin_amdgcn_perm(PB.u[1], PB.u[0], 0x05040100u) & 0xFFF0FFF0u; \
    lo_.u[3] = __builtin_amdgcn_perm(PB.u[3], PB.u[2], 0x05040100u) & 0xFFF0FFF0u; \
    a0 = MFMA16(hi_.h, Ur[0][c], a0);                                        \
    a1 = MFMA16(hi_.h, Ur[1][c], a1);                                        \
    a2 = MFMA16(hi_.h, Ur[2][c], a2);                                        \
    a3 = MFMA16(hi_.h, Ur[3][c], a3);                                        \
    a0 = MFMA16(lo_.h, Ur[0][c], a0);                                        \
    a1 = MFMA16(lo_.h, Ur[1][c], a1);                                        \
    a2 = MFMA16(lo_.h, Ur[2][c], a2);                                        \
    a3 = MFMA16(lo_.h, Ur[3][c], a3);                                        \
  } while (0)

#define XW(c, xv)                                                            \
  a0 = MFMA16(xv.h, Wr[0][c], a0);                                           \
  a1 = MFMA16(xv.h, Wr[1][c], a1);                                           \
  a2 = MFMA16(xv.h, Wr[2][c], a2);                                           \
  a3 = MFMA16(xv.h, Wr[3][c], a3);

// plain (L2-cached) x loads into XL set
#define ISSUE_X(X0, X1, X2, X3, ptr)                                         \
  asm volatile(                                                              \
      "global_load_dwordx4 %0, %4, off\n\t"                                  \
      "global_load_dwordx4 %1, %4, off offset:64\n\t"                        \
      "global_load_dwordx4 %2, %4, off offset:128\n\t"                       \
      "global_load_dwordx4 %3, %4, off offset:192"                           \
      : "=v"(X0.f), "=v"(X1.f), "=v"(X2.f), "=v"(X3.f)                       \
      : "v"(ptr)                                                             \
      : "memory")

// epilogue shared by prologue and bodies (PAR = EX parity = t&1)
#define EPILOGUE(T, PAR)                                                     \
  do {                                                                       \
    _Pragma("unroll")                                                        \
    for (int G = 0; G < 4; ++G) {                                            \
      f32x4 av = (G == 0) ? a0 : (G == 1) ? a1 : (G == 2) ? a2 : a3;         \
      _Pragma("unroll")                                                      \
      for (int r = 0; r < 4; ++r) EX[PAR][wv][G][l4 * 4 + r][l15] = av[r];   \
    }                                                                        \
    __syncthreads();                                                         \
    float z0 = EX[PAR][0][0][urow][ucol] + EX[PAR][1][0][urow][ucol] +       \
               EX[PAR][2][0][urow][ucol] + EX[PAR][3][0][urow][ucol] + b4[0];\
    float z1 = EX[PAR][0][1][urow][ucol] + EX[PAR][1][1][urow][ucol] +       \
               EX[PAR][2][1][urow][ucol] + EX[PAR][3][1][urow][ucol] + b4[1];\
    float z2 = EX[PAR][0][2][urow][ucol] + EX[PAR][1][2][urow][ucol] +       \
               EX[PAR][2][2][urow][ucol] + EX[PAR][3][2][urow][ucol] + b4[2];\
    float z3 = EX[PAR][0][3][urow][ucol] + EX[PAR][1][3][urow][ucol] +       \
               EX[PAR][2][3][urow][ucol] + EX[PAR][3][3][urow][ucol] + b4[3];\
    float ig = sigmoid_f(z0), fg = sigmoid_f(z1);                            \
    float ct = tanh_f(z2), og = sigmoid_f(z3);                               \
    float cn = tanh_f(fg * cstate + ig * ct);                                \
    cstate = cn;                                                             \
    float h = og * cn;                                                       \
    bu16 hh; hh.b = (bf16_t)h;                                               \
    bu16 hl; hl.b = (bf16_t)(h - (float)hh.b);                               \
    uint32_t pubw = ((uint32_t)hh.u << 16) | ((uint32_t)hl.u & 0xFFF0u) |    \
                    ((uint32_t)((T) + 1) & 15u);                             \
    uint32_t* dstp = hpub + ((PAR) ? BH : 0);                                \
    asm volatile("global_store_dword %0, %1, off sc0 sc1" ::"v"(dstp),       \
                 "v"(pubw) : "memory");                                      \
    float* outw = outp + (size_t)(T) * Hdim;                                 \
    asm volatile("global_store_dword %0, %1, off nt" ::"v"(outw), "v"(h)     \
                 : "memory");                                                \
  } while (0)

// full step body, t>=1.  XU = x_t regs (ready), XL = regs to load x_{t+1}.
// PAR = t&1 (write plane/EX parity); read plane = 1-PAR.
#define BODY(T, XU0, XU1, XU2, XU3, XL0, XL1, XL2, XL3, PAR)                 \
  do {                                                                       \
    const int t_ = (T);                                                      \
    asm volatile("s_waitcnt vmcnt(2)" ::: "memory"); /* XU ready */          \
    __builtin_amdgcn_sched_barrier(0);                                       \
    const uint32_t st = (uint32_t)t_ & 15u;                                  \
    const uint32_t* hb = hrd + ((PAR) ? 0 : BH); /* plane (t-1)&1 */         \
    pv128 p0, p1, p2, p3, p4, p5, p6, p7;                                    \
    ISSUE_POLL();                                                            \
    {                                                                        \
      const bf16_t* xp_ =                                                    \
          xrow + (size_t)((t_ + 1 < Tdim) ? t_ + 1 : Tdim - 1) * Ddim;       \
      ISSUE_X(XL0, XL1, XL2, XL3, xp_);                                      \
    }                                                                        \
    f32x4 a0 = {0, 0, 0, 0}, a1 = {0, 0, 0, 0};                              \
    f32x4 a2 = {0, 0, 0, 0}, a3 = {0, 0, 0, 0};                              \
    XW(0, XU0) XW(1, XU1) XW(2, XU2) XW(3, XU3)                              \
    {                                                                        \
      uint32_t bad;                                                          \
      asm volatile("s_waitcnt vmcnt(4)" ::: "memory"); /* polls done */      \
      __builtin_amdgcn_sched_barrier(0);                                     \
      CHECK8();                                                              \
      if (!__all(bad == 0)) {                                                \
        int guard = 0;                                                       \
        for (;;) {                                                           \
          ISSUE_POLL();                                                      \
          asm volatile("s_waitcnt vmcnt(0)" ::: "memory");                   \
          __builtin_amdgcn_sched_barrier(0);                                 \
          CHECK8();                                                          \
          if (__all(bad == 0)) break;                                        \
          if (++guard > 200000) break;                                       \
        }                                                                    \
      }                                                                      \
    }                                                                        \
    HU(p0, p1, 0);                                                           \
    HU(p2, p3, 1);                                                           \
    HU(p4, p5, 2);                                                           \
    HU(p6, p7, 3);                                                           \
    EPILOGUE(t_, PAR);                                                       \
  } while (0)

__launch_bounds__(256, 1)
__global__ void lstm_fused(const bf16_t* __restrict__ xb,   // [B][T][D] bf16
                           const bf16_t* __restrict__ Wt,   // [2048][512] bf16
                           const bf16_t* __restrict__ Ut,   // [2048][512] bf16
                           const float* __restrict__ bias,  // [2048]
                           float* __restrict__ out,         // [B][T][H] fp32
                           uint32_t* __restrict__ hbuf) {   // [2 par][B][H] u32
  __shared__ float EX[2][4][4][16][17];  // [parity][wave][gate][row][col]

  const int blk  = blockIdx.x;
  const int g    = blk >> 5;
  const int s    = blk & 31;
  const int wv   = threadIdx.x >> 6;
  const int lane = threadIdx.x & 63;
  const int l15  = lane & 15;
  const int l4   = lane >> 4;
  const int b0   = g * 16;
  const int hc0  = s * 16;
  const int k0   = wv * 128;

  // ---- weights into registers (MFMA B-frag order) ----
  bf16x8 Wr[4][4], Ur[4][4];
#pragma unroll
  for (int G = 0; G < 4; ++G) {
    const bf16_t* wsrc = Wt + (size_t)(G * Hdim + hc0 + l15) * Ddim + k0 + l4 * 8;
    const bf16_t* usrc = Ut + (size_t)(G * Hdim + hc0 + l15) * Ddim + k0 + l4 * 8;
#pragma unroll
    for (int c = 0; c < 4; ++c) {
      Wr[G][c] = *(const bf16x8*)(wsrc + c * 32);
      Ur[G][c] = *(const bf16x8*)(usrc + c * 32);
    }
  }

  const int urow = threadIdx.x >> 4;
  const int ucol = threadIdx.x & 15;
  float b4[4];
#pragma unroll
  for (int G = 0; G < 4; ++G) b4[G] = bias[G * Hdim + hc0 + ucol];
  float cstate = 0.f;
  float* outp = out + (size_t)(b0 + urow) * Tdim * Hdim + hc0 + ucol;
  uint32_t* hpub = hbuf + (size_t)(b0 + urow) * Hdim + hc0 + ucol;
  const uint32_t* hrd = hbuf + (size_t)(b0 + l15) * Hdim + k0 + l4 * 8;
  const bf16_t* xrow = xb + (size_t)(b0 + l15) * Tdim * Ddim + l4 * 8 + k0;

  pv128 xA0, xA1, xA2, xA3, xB0, xB1, xB2, xB3;

  // ---- prologue t = 0: load x_0, compute (no h), publish, issue x_1 ----
  ISSUE_X(xA0, xA1, xA2, xA3, xrow);
  asm volatile("s_waitcnt vmcnt(0)" ::: "memory");
  __builtin_amdgcn_sched_barrier(0);
  {
    // issue x_1 into xB BEFORE any stores (keeps stores youngest for vmcnt(2))
    ISSUE_X(xB0, xB1, xB2, xB3, xrow + (size_t)Ddim);
    f32x4 a0 = {0, 0, 0, 0}, a1 = {0, 0, 0, 0};
    f32x4 a2 = {0, 0, 0, 0}, a3 = {0, 0, 0, 0};
    XW(0, xA0) XW(1, xA1) XW(2, xA2) XW(3, xA3)
    EPILOGUE(0, 0);
  }

  // ---- main loop: pairs (odd t uses xB, even t uses xA) ----
  for (int t = 1; t < 511; t += 2) {
    BODY(t,     xB0, xB1, xB2, xB3, xA0, xA1, xA2, xA3, 1);
    BODY(t + 1, xA0, xA1, xA2, xA3, xB0, xB1, xB2, xB3, 0);
  }
  // ---- final step t = 511 (uniform body; dummy x load, never consumed) ----
  BODY(511, xB0, xB1, xB2, xB3, xA0, xA1, xA2, xA3, 1);
}

extern "C" void kernel_launch(void* const* d_in, const int* in_sizes, int n_in,
                              void* d_out, int out_size, void* d_ws, size_t ws_size,
                              hipStream_t stream) {
  const float* x    = (const float*)d_in[0];
  const float* W    = (const float*)d_in[1];
  const float* U    = (const float*)d_in[2];
  const float* bias = (const float*)d_in[3];
  float* out = (float*)d_out;

  unsigned char* ws = (unsigned char*)d_ws;
  // layout: hbuf 256 KB (memset each call) | Wt 2 MB | Ut 2 MB | xb 32 MB
  uint32_t* hbuf = (uint32_t*)ws;
  bf16_t* Wt = (bf16_t*)(ws + 262144);
  bf16_t* Ut = Wt + (size_t)G4H * Ddim;
  bf16_t* xb = Ut + (size_t)G4H * Ddim;

  hipMemsetAsync(hbuf, 0, 262144, stream);

  cast_bf16<<<(Bdim * Tdim * Ddim) / 2048, 256, 0, stream>>>(x, xb);

  dim3 tgrid(G4H / 64, Ddim / 64);
  transpose_bf16_512x2048<<<tgrid, 256, 0, stream>>>(W, Wt);
  transpose_bf16_512x2048<<<tgrid, 256, 0, stream>>>(U, Ut);

  lstm_fused<<<NG * NS, 256, 0, stream>>>(xb, Wt, Ut, bias, out, hbuf);
}

// Round 8
// 1824.438 us; speedup vs baseline: 1.0696x; 1.0696x over previous
//
#include <hip/hip_runtime.h>
#include <hip/hip_bf16.h>
#include <stdint.h>

// LSTM forward, B=64 T=512 D=512 H=512, return_sequences.
// v8 = v6 (proven 1526us) + flag-gated poll retries.
// 128 blocks = 4 batch-groups x 32 col-slices. Waves split k (128 each):
// weights in VGPRs; each wave polls its 8 producer slices' h data (MALL,
// sc0 sc1, flag-in-data stamping). First poll = bulk (steady-state hit).
// On miss: spin on tiny per-(slice,wave) hint flags (2KB/round vs 32KB),
// then ONE bulk refetch (stamp-verified; flags are hints only).
// Kept from v7: CHECK8, v_perm unpack, EX[2] single barrier.
// Kept from v6: x nt loads issued after HU, end-of-step vmcnt(0) drain.

#define Bdim 64
#define Tdim 512
#define Ddim 512
#define Hdim 512
#define G4H  2048
#define NG 4
#define NS 32
#define BH (Bdim * Hdim)  // u32 elems per parity plane

typedef __bf16 bf16_t;
typedef __bf16 bf16x8 __attribute__((ext_vector_type(8)));
typedef float  f32x4  __attribute__((ext_vector_type(4)));
typedef uint32_t u32x4 __attribute__((ext_vector_type(4)));
union pv128 { u32x4 u; f32x4 f; bf16x8 h; };
union bu16 { bf16_t b; unsigned short u; };

__device__ __forceinline__ float sigmoid_f(float x) {
  return 1.0f / (1.0f + __expf(-x));
}
__device__ __forceinline__ float tanh_f(float x) {
  return 1.0f - 2.0f / (__expf(2.0f * x) + 1.0f);  // stable both tails
}

// src [512][2048] fp32  ->  dst [2048][512] bf16 (transposed)
__global__ void transpose_bf16_512x2048(const float* __restrict__ src,
                                        bf16_t* __restrict__ dst) {
  __shared__ bf16_t tile[64][72];
  int c0 = blockIdx.x * 64;
  int r0 = blockIdx.y * 64;
  int tx = threadIdx.x & 63;
  int ty = threadIdx.x >> 6;
#pragma unroll
  for (int i = 0; i < 64; i += 4)
    tile[ty + i][tx] = (bf16_t)src[(size_t)(r0 + ty + i) * G4H + c0 + tx];
  __syncthreads();
#pragma unroll
  for (int i = 0; i < 64; i += 4)
    dst[(size_t)(c0 + ty + i) * Ddim + r0 + tx] = tile[tx][ty + i];
}

// fp32 -> bf16 elementwise (x pre-conversion), 8 elems/thread
__global__ void cast_bf16(const float* __restrict__ in, bf16_t* __restrict__ out) {
  size_t i = ((size_t)blockIdx.x * blockDim.x + threadIdx.x) * 8;
  f32x4 a = *(const f32x4*)(in + i);
  f32x4 b = *(const f32x4*)(in + i + 4);
  bf16x8 v;
#pragma unroll
  for (int j = 0; j < 4; ++j) { v[j] = (bf16_t)a[j]; v[j + 4] = (bf16_t)b[j]; }
  *(bf16x8*)(out + i) = v;
}

#define MFMA16(A, B, C) __builtin_amdgcn_mfma_f32_16x16x32_bf16(A, B, C, 0, 0, 0)

// 8 stamped h loads (2 per k-chunk), MALL-direct
#define ISSUE_POLL()                                                         \
  asm volatile(                                                              \
      "global_load_dwordx4 %0, %8, off sc0 sc1\n\t"                          \
      "global_load_dwordx4 %1, %8, off offset:16 sc0 sc1\n\t"                \
      "global_load_dwordx4 %2, %8, off offset:128 sc0 sc1\n\t"               \
      "global_load_dwordx4 %3, %8, off offset:144 sc0 sc1\n\t"               \
      "global_load_dwordx4 %4, %8, off offset:256 sc0 sc1\n\t"               \
      "global_load_dwordx4 %5, %8, off offset:272 sc0 sc1\n\t"               \
      "global_load_dwordx4 %6, %8, off offset:384 sc0 sc1\n\t"               \
      "global_load_dwordx4 %7, %8, off offset:400 sc0 sc1"                   \
      : "=v"(p0.f), "=v"(p1.f), "=v"(p2.f), "=v"(p3.f), "=v"(p4.f),          \
        "=v"(p5.f), "=v"(p6.f), "=v"(p7.f)                                   \
      : "v"(hb)                                                              \
      : "memory")

// one stamp check per 16B load (producer 64B-line wave stores; v7-verified)
#define CHECK8()                                                             \
  do {                                                                       \
    bad = (p0.u[0] ^ st) & 15u;                                              \
    bad |= (p1.u[0] ^ st) & 15u;                                             \
    bad |= (p2.u[0] ^ st) & 15u;                                             \
    bad |= (p3.u[0] ^ st) & 15u;                                             \
    bad |= (p4.u[0] ^ st) & 15u;                                             \
    bad |= (p5.u[0] ^ st) & 15u;                                             \
    bad |= (p6.u[0] ^ st) & 15u;                                             \
    bad |= (p7.u[0] ^ st) & 15u;                                             \
  } while (0)

// unpack chunk c (8 u32 -> hi/lo bf16x8 via v_perm) and run 8 MFMAs
#define HU(PA, PB, c)                                                        \
  do {                                                                       \
    pv128 hi_, lo_;                                                          \
    hi_.u[0] = __builtin_amdgcn_perm(PA.u[1], PA.u[0], 0x07060302u);         \
    hi_.u[1] = __builtin_amdgcn_perm(PA.u[3], PA.u[2], 0x07060302u);         \
    hi_.u[2] = __builtin_amdgcn_perm(PB.u[1], PB.u[0], 0x07060302u);         \
    hi_.u[3] = __builtin_amdgcn_perm(PB.u[3], PB.u[2], 0x07060302u);         \
    lo_.u[0] = __builtin_amdgcn_perm(PA.u[1], PA.u[0], 0x05040100u) & 0xFFF0FFF0u; \
    lo_.u[1] = __builtin_amdgcn_perm(PA.u[3], PA.u[2], 0x05040100u) & 0xFFF0FFF0u; \
    lo_.u[2] = __builtin_amdgcn_perm(PB.u[1], PB.u[0], 0x05040100u) & 0xFFF0FFF0u; \
    lo_.u[3] = __builtin_amdgcn_perm(PB.u[3], PB.u[2], 0x05040100u) & 0xFFF0FFF0u; \
    a0 = MFMA16(hi_.h, Ur[0][c], a0);                                        \
    a1 = MFMA16(hi_.h, Ur[1][c], a1);                                        \
    a2 = MFMA16(hi_.h, Ur[2][c], a2);                                        \
    a3 = MFMA16(hi_.h, Ur[3][c], a3);                                        \
    a0 = MFMA16(lo_.h, Ur[0][c], a0);                                        \
    a1 = MFMA16(lo_.h, Ur[1][c], a1);                                        \
    a2 = MFMA16(lo_.h, Ur[2][c], a2);                                        \
    a3 = MFMA16(lo_.h, Ur[3][c], a3);                                        \
  } while (0)

__launch_bounds__(256, 1)
__global__ void lstm_fused(const bf16_t* __restrict__ xb,   // [B][T][D] bf16
                           const bf16_t* __restrict__ Wt,   // [2048][512] bf16
                           const bf16_t* __restrict__ Ut,   // [2048][512] bf16
                           const float* __restrict__ bias,  // [2048]
                           float* __restrict__ out,         // [B][T][H] fp32
                           uint32_t* __restrict__ hbuf,     // [2 par][B][H] u32
                           uint32_t* __restrict__ flags) {  // [NG*NS][4] x16 u32
  __shared__ float EX[2][4][4][16][17];  // [parity][wave][gate][row][col]

  const int blk  = blockIdx.x;
  const int g    = blk >> 5;
  const int s    = blk & 31;
  const int wv   = threadIdx.x >> 6;
  const int lane = threadIdx.x & 63;
  const int l15  = lane & 15;
  const int l4   = lane >> 4;
  const int b0   = g * 16;
  const int hc0  = s * 16;
  const int k0   = wv * 128;

  // ---- weights into registers (MFMA B-frag order) ----
  bf16x8 Wr[4][4], Ur[4][4];
#pragma unroll
  for (int G = 0; G < 4; ++G) {
    const bf16_t* wsrc = Wt + (size_t)(G * Hdim + hc0 + l15) * Ddim + k0 + l4 * 8;
    const bf16_t* usrc = Ut + (size_t)(G * Hdim + hc0 + l15) * Ddim + k0 + l4 * 8;
#pragma unroll
    for (int c = 0; c < 4; ++c) {
      Wr[G][c] = *(const bf16x8*)(wsrc + c * 32);
      Ur[G][c] = *(const bf16x8*)(usrc + c * 32);
    }
  }

  const int urow = threadIdx.x >> 4;
  const int ucol = threadIdx.x & 15;
  float b4[4];
#pragma unroll
  for (int G = 0; G < 4; ++G) b4[G] = bias[G * Hdim + hc0 + ucol];
  float cstate = 0.f;
  float* outp = out + (size_t)(b0 + urow) * Tdim * Hdim + hc0 + ucol;
  uint32_t* hpub = hbuf + (size_t)(b0 + urow) * Hdim + hc0 + ucol;
  const uint32_t* hrd = hbuf + (size_t)(b0 + l15) * Hdim + k0 + l4 * 8;
  const bf16_t* xrow = xb + (size_t)(b0 + l15) * Tdim * Ddim + l4 * 8 + k0;

  // hint flags: publish slot for (g,s,wv); poll set = 8 producer slices x 4 waves
  uint32_t* fpub = flags + ((size_t)(g * NS + s) * 4 + wv) * 16;
  const uint32_t* fpoll =
      flags + ((size_t)(g * NS + wv * 8 + ((lane >> 2) & 7)) * 4 + (lane & 3)) * 16;

  // ---- prologue: x(0) into regs ----
  pv128 xr0, xr1, xr2, xr3;
  asm volatile(
      "global_load_dwordx4 %0, %4, off nt\n\t"
      "global_load_dwordx4 %1, %4, off offset:64 nt\n\t"
      "global_load_dwordx4 %2, %4, off offset:128 nt\n\t"
      "global_load_dwordx4 %3, %4, off offset:192 nt\n\t"
      "s_waitcnt vmcnt(0)"
      : "=v"(xr0.f), "=v"(xr1.f), "=v"(xr2.f), "=v"(xr3.f)
      : "v"(xrow) : "memory");
  __builtin_amdgcn_sched_barrier(0);

  for (int t = 0; t < Tdim; ++t) {
    pv128 p0, p1, p2, p3, p4, p5, p6, p7;
    const uint32_t st = (uint32_t)t & 15u;  // stamp on h_{t-1}
    const uint32_t* hb = hrd + (((t - 1) & 1) ? BH : 0);

    // [P] issue stamped bulk h polls; they fly during x@W
    if (t > 0) {
      ISSUE_POLL();
      __builtin_amdgcn_sched_barrier(0);
    }

    // [A] x_t @ W (registers only)
    f32x4 a0 = {0, 0, 0, 0}, a1 = {0, 0, 0, 0}, a2 = {0, 0, 0, 0}, a3 = {0, 0, 0, 0};
#define XW(c, xv)                                                            \
    a0 = MFMA16(xv.h, Wr[0][c], a0);                                         \
    a1 = MFMA16(xv.h, Wr[1][c], a1);                                         \
    a2 = MFMA16(xv.h, Wr[2][c], a2);                                         \
    a3 = MFMA16(xv.h, Wr[3][c], a3);
    XW(0, xr0) XW(1, xr1) XW(2, xr2) XW(3, xr3)
#undef XW

    if (t > 0) {
      // [C] first bulk check; on miss -> cheap flag spin -> one bulk refetch
      uint32_t bad;
      asm volatile("s_waitcnt vmcnt(0)" ::: "memory");
      __builtin_amdgcn_sched_barrier(0);
      CHECK8();
      if (!__all(bad == 0)) {
        int guard = 0;
        // cheap spin: 32 hint dwords (lanes duplicated 32-63), 2KB/round
        for (;;) {
          uint32_t fv;
          asm volatile("global_load_dword %0, %1, off sc0 sc1\n\t"
                       "s_waitcnt vmcnt(0)"
                       : "=v"(fv) : "v"(fpoll) : "memory");
          if (__all((int)(fv >= (uint32_t)t))) break;
          if (++guard > 500000) break;
        }
        // bulk refetch, stamp-verified (flags are hints only)
        for (;;) {
          ISSUE_POLL();
          asm volatile("s_waitcnt vmcnt(0)" ::: "memory");
          __builtin_amdgcn_sched_barrier(0);
          CHECK8();
          if (__all(bad == 0)) break;
          if (++guard > 500000) break;
        }
      }
      // [U] unpack + h @ U (hi + lo)
      HU(p0, p1, 0);
      HU(p2, p3, 1);
      HU(p4, p5, 2);
      HU(p6, p7, 3);
    }

    // [D] prefetch x(t+1) (nt, consumed next step)
    {
      const bf16_t* xp = xrow + (size_t)((t + 1 < Tdim) ? t + 1 : Tdim - 1) * Ddim;
      asm volatile(
          "global_load_dwordx4 %0, %4, off nt\n\t"
          "global_load_dwordx4 %1, %4, off offset:64 nt\n\t"
          "global_load_dwordx4 %2, %4, off offset:128 nt\n\t"
          "global_load_dwordx4 %3, %4, off offset:192 nt"
          : "=v"(xr0.f), "=v"(xr1.f), "=v"(xr2.f), "=v"(xr3.f)
          : "v"(xp) : "memory");
    }

    // [G] k-partial z -> LDS (parity buffer)
    const int par = t & 1;
#pragma unroll
    for (int G = 0; G < 4; ++G) {
      f32x4 av = (G == 0) ? a0 : (G == 1) ? a1 : (G == 2) ? a2 : a3;
#pragma unroll
      for (int r = 0; r < 4; ++r) EX[par][wv][G][l4 * 4 + r][l15] = av[r];
    }
    __syncthreads();

    // [H] per-element update + direct stamped publish
    float z0 = EX[par][0][0][urow][ucol] + EX[par][1][0][urow][ucol] +
               EX[par][2][0][urow][ucol] + EX[par][3][0][urow][ucol] + b4[0];
    float z1 = EX[par][0][1][urow][ucol] + EX[par][1][1][urow][ucol] +
               EX[par][2][1][urow][ucol] + EX[par][3][1][urow][ucol] + b4[1];
    float z2 = EX[par][0][2][urow][ucol] + EX[par][1][2][urow][ucol] +
               EX[par][2][2][urow][ucol] + EX[par][3][2][urow][ucol] + b4[2];
    float z3 = EX[par][0][3][urow][ucol] + EX[par][1][3][urow][ucol] +
               EX[par][2][3][urow][ucol] + EX[par][3][3][urow][ucol] + b4[3];
    float ig = sigmoid_f(z0), fg = sigmoid_f(z1);
    float ct = tanh_f(z2), og = sigmoid_f(z3);
    float cn = tanh_f(fg * cstate + ig * ct);  // module carries ACTIVATED cell
    cstate = cn;
    float h = og * cn;

    bu16 hh; hh.b = (bf16_t)h;
    bu16 hl; hl.b = (bf16_t)(h - (float)hh.b);
    uint32_t pubw = ((uint32_t)hh.u << 16) | ((uint32_t)hl.u & 0xFFF0u) |
                    ((uint32_t)(t + 1) & 15u);
    uint32_t* dst = hpub + (par ? BH : 0);
    asm volatile("global_store_dword %0, %1, off sc0 sc1" ::"v"(dst), "v"(pubw)
                 : "memory");
    __builtin_nontemporal_store(h, outp + (size_t)t * Hdim);

    // per-wave hint flag (after data stores in program order; no ack wait —
    // consumers re-verify data stamps, so OOO visibility is safe)
    if (lane == 0) {
      uint32_t stamp = (uint32_t)(t + 1);
      asm volatile("global_store_dword %0, %1, off sc0 sc1" ::"v"(fpub),
                   "v"(stamp) : "memory");
    }

    // [J] drain x prefetch (and stores) before next [A]
    asm volatile("s_waitcnt vmcnt(0)" ::: "memory");
    __builtin_amdgcn_sched_barrier(0);
  }
}

extern "C" void kernel_launch(void* const* d_in, const int* in_sizes, int n_in,
                              void* d_out, int out_size, void* d_ws, size_t ws_size,
                              hipStream_t stream) {
  const float* x    = (const float*)d_in[0];
  const float* W    = (const float*)d_in[1];
  const float* U    = (const float*)d_in[2];
  const float* bias = (const float*)d_in[3];
  float* out = (float*)d_out;

  unsigned char* ws = (unsigned char*)d_ws;
  // layout: flags 32 KB | hbuf 256 KB (both memset) | Wt 2 MB | Ut 2 MB | xb 32 MB
  uint32_t* flags = (uint32_t*)ws;
  uint32_t* hbuf  = (uint32_t*)(ws + 32768);
  bf16_t* Wt = (bf16_t*)(ws + 32768 + 262144);
  bf16_t* Ut = Wt + (size_t)G4H * Ddim;
  bf16_t* xb = Ut + (size_t)G4H * Ddim;

  hipMemsetAsync(ws, 0, 32768 + 262144, stream);

  cast_bf16<<<(Bdim * Tdim * Ddim) / 2048, 256, 0, stream>>>(x, xb);

  dim3 tgrid(G4H / 64, Ddim / 64);
  transpose_bf16_512x2048<<<tgrid, 256, 0, stream>>>(W, Wt);
  transpose_bf16_512x2048<<<tgrid, 256, 0, stream>>>(U, Ut);

  lstm_fused<<<NG * NS, 256, 0, stream>>>(xb, Wt, Ut, bias, out, hbuf, flags);
}

// Round 9
// 1467.753 us; speedup vs baseline: 1.3296x; 1.2430x over previous
//
#include <hip/hip_runtime.h>
#include <hip/hip_bf16.h>
#include <stdint.h>

// LSTM forward, B=64 T=512 D=512 H=512, return_sequences.
// v9 = v6 (proven 1526us) with EXACTLY ONE change: x loads are plain
// (L2-cacheable) instead of nt. Everything else byte-identical to v6.
// Rationale: v6's FETCH_SIZE (~826 KB/step) is dominated by nt x loads
// re-fetched from HBM each step; their ~900cy latency sits inside the
// end-of-step vmcnt(0) drain with only ~300cy of epilogue to hide it.
// Plain loads make x L2-resident per XCD (~200cy, no HBM traffic).

#define Bdim 64
#define Tdim 512
#define Ddim 512
#define Hdim 512
#define G4H  2048
#define NG 4
#define NS 32
#define BH (Bdim * Hdim)  // u32 elems per parity plane

typedef __bf16 bf16_t;
typedef __bf16 bf16x8 __attribute__((ext_vector_type(8)));
typedef float  f32x4  __attribute__((ext_vector_type(4)));
typedef uint32_t u32x4 __attribute__((ext_vector_type(4)));
union pv128 { u32x4 u; f32x4 f; bf16x8 h; };
union bu16 { bf16_t b; unsigned short u; };

__device__ __forceinline__ float sigmoid_f(float x) {
  return 1.0f / (1.0f + __expf(-x));
}
__device__ __forceinline__ float tanh_f(float x) {
  return 1.0f - 2.0f / (__expf(2.0f * x) + 1.0f);  // stable both tails
}

// src [512][2048] fp32  ->  dst [2048][512] bf16 (transposed)
__global__ void transpose_bf16_512x2048(const float* __restrict__ src,
                                        bf16_t* __restrict__ dst) {
  __shared__ bf16_t tile[64][72];
  int c0 = blockIdx.x * 64;
  int r0 = blockIdx.y * 64;
  int tx = threadIdx.x & 63;
  int ty = threadIdx.x >> 6;
#pragma unroll
  for (int i = 0; i < 64; i += 4)
    tile[ty + i][tx] = (bf16_t)src[(size_t)(r0 + ty + i) * G4H + c0 + tx];
  __syncthreads();
#pragma unroll
  for (int i = 0; i < 64; i += 4)
    dst[(size_t)(c0 + ty + i) * Ddim + r0 + tx] = tile[tx][ty + i];
}

// fp32 -> bf16 elementwise (x pre-conversion), 8 elems/thread
__global__ void cast_bf16(const float* __restrict__ in, bf16_t* __restrict__ out) {
  size_t i = ((size_t)blockIdx.x * blockDim.x + threadIdx.x) * 8;
  f32x4 a = *(const f32x4*)(in + i);
  f32x4 b = *(const f32x4*)(in + i + 4);
  bf16x8 v;
#pragma unroll
  for (int j = 0; j < 4; ++j) { v[j] = (bf16_t)a[j]; v[j + 4] = (bf16_t)b[j]; }
  *(bf16x8*)(out + i) = v;
}

#define MFMA16(A, B, C) __builtin_amdgcn_mfma_f32_16x16x32_bf16(A, B, C, 0, 0, 0)

// 8 stamped h loads (2 per k-chunk), MALL-direct
#define ISSUE_POLL()                                                         \
  asm volatile(                                                              \
      "global_load_dwordx4 %0, %8, off sc0 sc1\n\t"                          \
      "global_load_dwordx4 %1, %8, off offset:16 sc0 sc1\n\t"                \
      "global_load_dwordx4 %2, %8, off offset:128 sc0 sc1\n\t"               \
      "global_load_dwordx4 %3, %8, off offset:144 sc0 sc1\n\t"               \
      "global_load_dwordx4 %4, %8, off offset:256 sc0 sc1\n\t"               \
      "global_load_dwordx4 %5, %8, off offset:272 sc0 sc1\n\t"               \
      "global_load_dwordx4 %6, %8, off offset:384 sc0 sc1\n\t"               \
      "global_load_dwordx4 %7, %8, off offset:400 sc0 sc1"                   \
      : "=v"(p0.f), "=v"(p1.f), "=v"(p2.f), "=v"(p3.f), "=v"(p4.f),          \
        "=v"(p5.f), "=v"(p6.f), "=v"(p7.f)                                   \
      : "v"(hb)                                                              \
      : "memory")

#define CHECK(P)                                                             \
  do {                                                                       \
    bad |= (P.u[0] ^ st) & 15u;                                              \
    bad |= (P.u[1] ^ st) & 15u;                                              \
    bad |= (P.u[2] ^ st) & 15u;                                              \
    bad |= (P.u[3] ^ st) & 15u;                                              \
  } while (0)

// unpack chunk c (8 u32 -> hi/lo bf16x8) and run 8 MFMAs
#define HU(PA, PB, c)                                                        \
  do {                                                                       \
    pv128 hi_, lo_;                                                          \
    hi_.u[0] = (PA.u[0] >> 16) | (PA.u[1] & 0xFFFF0000u);                    \
    hi_.u[1] = (PA.u[2] >> 16) | (PA.u[3] & 0xFFFF0000u);                    \
    hi_.u[2] = (PB.u[0] >> 16) | (PB.u[1] & 0xFFFF0000u);                    \
    hi_.u[3] = (PB.u[2] >> 16) | (PB.u[3] & 0xFFFF0000u);                    \
    lo_.u[0] = (PA.u[0] & 0xFFF0u) | ((PA.u[1] & 0xFFF0u) << 16);            \
    lo_.u[1] = (PA.u[2] & 0xFFF0u) | ((PA.u[3] & 0xFFF0u) << 16);            \
    lo_.u[2] = (PB.u[0] & 0xFFF0u) | ((PB.u[1] & 0xFFF0u) << 16);            \
    lo_.u[3] = (PB.u[2] & 0xFFF0u) | ((PB.u[3] & 0xFFF0u) << 16);            \
    a0 = MFMA16(hi_.h, Ur[0][c], a0);                                        \
    a1 = MFMA16(hi_.h, Ur[1][c], a1);                                        \
    a2 = MFMA16(hi_.h, Ur[2][c], a2);                                        \
    a3 = MFMA16(hi_.h, Ur[3][c], a3);                                        \
    a0 = MFMA16(lo_.h, Ur[0][c], a0);                                        \
    a1 = MFMA16(lo_.h, Ur[1][c], a1);                                        \
    a2 = MFMA16(lo_.h, Ur[2][c], a2);                                        \
    a3 = MFMA16(lo_.h, Ur[3][c], a3);                                        \
  } while (0)

__launch_bounds__(256, 1)
__global__ void lstm_fused(const bf16_t* __restrict__ xb,   // [B][T][D] bf16
                           const bf16_t* __restrict__ Wt,   // [2048][512] bf16
                           const bf16_t* __restrict__ Ut,   // [2048][512] bf16
                           const float* __restrict__ bias,  // [2048]
                           float* __restrict__ out,         // [B][T][H] fp32
                           uint32_t* __restrict__ hbuf) {   // [2 par][B][H] u32
  __shared__ float EX[4][4][16][17];  // [wave][gate][row][col]

  const int blk  = blockIdx.x;
  const int g    = blk >> 5;
  const int s    = blk & 31;
  const int wv   = threadIdx.x >> 6;
  const int lane = threadIdx.x & 63;
  const int l15  = lane & 15;
  const int l4   = lane >> 4;
  const int b0   = g * 16;
  const int hc0  = s * 16;
  const int k0   = wv * 128;

  // ---- weights into registers (MFMA B-frag order) ----
  bf16x8 Wr[4][4], Ur[4][4];
#pragma unroll
  for (int G = 0; G < 4; ++G) {
    const bf16_t* wsrc = Wt + (size_t)(G * Hdim + hc0 + l15) * Ddim + k0 + l4 * 8;
    const bf16_t* usrc = Ut + (size_t)(G * Hdim + hc0 + l15) * Ddim + k0 + l4 * 8;
#pragma unroll
    for (int c = 0; c < 4; ++c) {
      Wr[G][c] = *(const bf16x8*)(wsrc + c * 32);
      Ur[G][c] = *(const bf16x8*)(usrc + c * 32);
    }
  }

  const int urow = threadIdx.x >> 4;
  const int ucol = threadIdx.x & 15;
  float b4[4];
#pragma unroll
  for (int G = 0; G < 4; ++G) b4[G] = bias[G * Hdim + hc0 + ucol];
  float cstate = 0.f;
  float* outp = out + (size_t)(b0 + urow) * Tdim * Hdim + hc0 + ucol;
  uint32_t* hpub = hbuf + (size_t)(b0 + urow) * Hdim + hc0 + ucol;
  const uint32_t* hrd = hbuf + (size_t)(b0 + l15) * Hdim + k0 + l4 * 8;
  const bf16_t* xrow = xb + (size_t)(b0 + l15) * Tdim * Ddim + l4 * 8 + k0;

  // ---- prologue: x(0) into regs (plain loads; only change vs v6) ----
  pv128 xr0, xr1, xr2, xr3;
  asm volatile(
      "global_load_dwordx4 %0, %4, off\n\t"
      "global_load_dwordx4 %1, %4, off offset:64\n\t"
      "global_load_dwordx4 %2, %4, off offset:128\n\t"
      "global_load_dwordx4 %3, %4, off offset:192\n\t"
      "s_waitcnt vmcnt(0)"
      : "=v"(xr0.f), "=v"(xr1.f), "=v"(xr2.f), "=v"(xr3.f)
      : "v"(xrow) : "memory");
  __builtin_amdgcn_sched_barrier(0);

  bool dead = false;

  for (int t = 0; t < Tdim; ++t) {
    pv128 p0, p1, p2, p3, p4, p5, p6, p7;
    const uint32_t st = (uint32_t)t & 15u;  // stamp on h_{t-1}
    const uint32_t* hb = hrd + (((t - 1) & 1) ? BH : 0);

    // [P] issue stamped h polls; they fly during x@W
    if (t > 0 && !dead) {
      ISSUE_POLL();
      __builtin_amdgcn_sched_barrier(0);
    }

    // [A] x_t @ W (registers only)
    f32x4 a0 = {0, 0, 0, 0}, a1 = {0, 0, 0, 0}, a2 = {0, 0, 0, 0}, a3 = {0, 0, 0, 0};
#define XW(c, xv)                                                            \
    a0 = MFMA16(xv.h, Wr[0][c], a0);                                         \
    a1 = MFMA16(xv.h, Wr[1][c], a1);                                         \
    a2 = MFMA16(xv.h, Wr[2][c], a2);                                         \
    a3 = MFMA16(xv.h, Wr[3][c], a3);
    XW(0, xr0) XW(1, xr1) XW(2, xr2) XW(3, xr3)
#undef XW

    if (t > 0) {
      // [C] poll until all 32 words carry stamp t
      if (!dead) {
        int guard = 0;
        for (;;) {
          asm volatile("s_waitcnt vmcnt(0)" ::: "memory");
          __builtin_amdgcn_sched_barrier(0);
          uint32_t bad = 0;
          CHECK(p0); CHECK(p1); CHECK(p2); CHECK(p3);
          CHECK(p4); CHECK(p5); CHECK(p6); CHECK(p7);
          if (__all(bad == 0)) break;
          if (++guard > 200000) { dead = true; break; }
          ISSUE_POLL();
          __builtin_amdgcn_sched_barrier(0);
        }
      } else {
        p0.u = p1.u = p2.u = p3.u = p4.u = p5.u = p6.u = p7.u = (u32x4)(0u);
      }
      // [U] unpack + h @ U (hi + lo)
      HU(p0, p1, 0);
      HU(p2, p3, 1);
      HU(p4, p5, 2);
      HU(p6, p7, 3);
    }

    // [D] prefetch x(t+1) (plain loads; only change vs v6)
    {
      const bf16_t* xp = xrow + (size_t)((t + 1 < Tdim) ? t + 1 : Tdim - 1) * Ddim;
      asm volatile(
          "global_load_dwordx4 %0, %4, off\n\t"
          "global_load_dwordx4 %1, %4, off offset:64\n\t"
          "global_load_dwordx4 %2, %4, off offset:128\n\t"
          "global_load_dwordx4 %3, %4, off offset:192"
          : "=v"(xr0.f), "=v"(xr1.f), "=v"(xr2.f), "=v"(xr3.f)
          : "v"(xp) : "memory");
    }

    // [G] k-partial z -> LDS
#pragma unroll
    for (int G = 0; G < 4; ++G) {
      f32x4 av = (G == 0) ? a0 : (G == 1) ? a1 : (G == 2) ? a2 : a3;
#pragma unroll
      for (int r = 0; r < 4; ++r) EX[wv][G][l4 * 4 + r][l15] = av[r];
    }
    __syncthreads();

    // [H] per-element update + direct stamped publish
    float z0 = EX[0][0][urow][ucol] + EX[1][0][urow][ucol] +
               EX[2][0][urow][ucol] + EX[3][0][urow][ucol] + b4[0];
    float z1 = EX[0][1][urow][ucol] + EX[1][1][urow][ucol] +
               EX[2][1][urow][ucol] + EX[3][1][urow][ucol] + b4[1];
    float z2 = EX[0][2][urow][ucol] + EX[1][2][urow][ucol] +
               EX[2][2][urow][ucol] + EX[3][2][urow][ucol] + b4[2];
    float z3 = EX[0][3][urow][ucol] + EX[1][3][urow][ucol] +
               EX[2][3][urow][ucol] + EX[3][3][urow][ucol] + b4[3];
    float ig = sigmoid_f(z0), fg = sigmoid_f(z1);
    float ct = tanh_f(z2), og = sigmoid_f(z3);
    float cn = tanh_f(fg * cstate + ig * ct);  // module carries ACTIVATED cell
    cstate = cn;
    float h = og * cn;

    bu16 hh; hh.b = (bf16_t)h;
    bu16 hl; hl.b = (bf16_t)(h - (float)hh.b);
    uint32_t pubw = ((uint32_t)hh.u << 16) | ((uint32_t)hl.u & 0xFFF0u) |
                    ((uint32_t)(t + 1) & 15u);
    uint32_t* dst = hpub + ((t & 1) ? BH : 0);
    asm volatile("global_store_dword %0, %1, off sc0 sc1" ::"v"(dst), "v"(pubw)
                 : "memory");
    __builtin_nontemporal_store(h, outp + (size_t)t * Hdim);

    __syncthreads();  // EX WAR protection (also keeps waves in lockstep)

    // [J] drain x prefetch (and stores) before next [A]
    asm volatile("s_waitcnt vmcnt(0)" ::: "memory");
    __builtin_amdgcn_sched_barrier(0);
  }
}

extern "C" void kernel_launch(void* const* d_in, const int* in_sizes, int n_in,
                              void* d_out, int out_size, void* d_ws, size_t ws_size,
                              hipStream_t stream) {
  const float* x    = (const float*)d_in[0];
  const float* W    = (const float*)d_in[1];
  const float* U    = (const float*)d_in[2];
  const float* bias = (const float*)d_in[3];
  float* out = (float*)d_out;

  unsigned char* ws = (unsigned char*)d_ws;
  // layout: hbuf 256 KB (memset each call) | Wt 2 MB | Ut 2 MB | xb 32 MB
  uint32_t* hbuf = (uint32_t*)ws;
  bf16_t* Wt = (bf16_t*)(ws + 262144);
  bf16_t* Ut = Wt + (size_t)G4H * Ddim;
  bf16_t* xb = Ut + (size_t)G4H * Ddim;

  hipMemsetAsync(hbuf, 0, 262144, stream);

  cast_bf16<<<(Bdim * Tdim * Ddim) / 2048, 256, 0, stream>>>(x, xb);

  dim3 tgrid(G4H / 64, Ddim / 64);
  transpose_bf16_512x2048<<<tgrid, 256, 0, stream>>>(W, Wt);
  transpose_bf16_512x2048<<<tgrid, 256, 0, stream>>>(U, Ut);

  lstm_fused<<<NG * NS, 256, 0, stream>>>(xb, Wt, Ut, bias, out, hbuf);
}

// Round 10
// 1381.097 us; speedup vs baseline: 1.4130x; 1.0627x over previous
//
#include <hip/hip_runtime.h>
#include <hip/hip_bf16.h>
#include <stdint.h>

// LSTM forward, B=64 T=512 D=512 H=512, return_sequences.
// v10 = v9 protocol/pacing, re-partitioned: 64 blocks = 4 groups x 16 slices
// (32 cols each), 512 threads = 8 waves, k-chunk 64/wave. Per-wave poll =
// 4 dwordx4 covering 2 producer slices (in-degree 8->2); chip poll BW halved.
// Weights in VGPRs (Wr/Ur[8][2]); EX [8][4][16][36] f32 in LDS; stamped-word
// MALL comm identical to v9 (sc0 sc1, bf16 hi/lo + 4-bit stamp, parity planes).

#define Bdim 64
#define Tdim 512
#define Ddim 512
#define Hdim 512
#define G4H  2048
#define NG 4
#define NS 16
#define BH (Bdim * Hdim)  // u32 elems per parity plane

typedef __bf16 bf16_t;
typedef __bf16 bf16x8 __attribute__((ext_vector_type(8)));
typedef float  f32x4  __attribute__((ext_vector_type(4)));
typedef uint32_t u32x4 __attribute__((ext_vector_type(4)));
union pv128 { u32x4 u; f32x4 f; bf16x8 h; };
union bu16 { bf16_t b; unsigned short u; };

__device__ __forceinline__ float sigmoid_f(float x) {
  return 1.0f / (1.0f + __expf(-x));
}
__device__ __forceinline__ float tanh_f(float x) {
  return 1.0f - 2.0f / (__expf(2.0f * x) + 1.0f);  // stable both tails
}

// src [512][2048] fp32  ->  dst [2048][512] bf16 (transposed)
__global__ void transpose_bf16_512x2048(const float* __restrict__ src,
                                        bf16_t* __restrict__ dst) {
  __shared__ bf16_t tile[64][72];
  int c0 = blockIdx.x * 64;
  int r0 = blockIdx.y * 64;
  int tx = threadIdx.x & 63;
  int ty = threadIdx.x >> 6;
#pragma unroll
  for (int i = 0; i < 64; i += 4)
    tile[ty + i][tx] = (bf16_t)src[(size_t)(r0 + ty + i) * G4H + c0 + tx];
  __syncthreads();
#pragma unroll
  for (int i = 0; i < 64; i += 4)
    dst[(size_t)(c0 + ty + i) * Ddim + r0 + tx] = tile[tx][ty + i];
}

// fp32 -> bf16 elementwise (x pre-conversion), 8 elems/thread
__global__ void cast_bf16(const float* __restrict__ in, bf16_t* __restrict__ out) {
  size_t i = ((size_t)blockIdx.x * blockDim.x + threadIdx.x) * 8;
  f32x4 a = *(const f32x4*)(in + i);
  f32x4 b = *(const f32x4*)(in + i + 4);
  bf16x8 v;
#pragma unroll
  for (int j = 0; j < 4; ++j) { v[j] = (bf16_t)a[j]; v[j + 4] = (bf16_t)b[j]; }
  *(bf16x8*)(out + i) = v;
}

#define MFMA16(A, B, C) __builtin_amdgcn_mfma_f32_16x16x32_bf16(A, B, C, 0, 0, 0)

// 4 stamped h loads (k-chunk 64 = 2 x 32-col chunks), MALL-direct
#define ISSUE_POLL()                                                         \
  asm volatile(                                                              \
      "global_load_dwordx4 %0, %4, off sc0 sc1\n\t"                          \
      "global_load_dwordx4 %1, %4, off offset:16 sc0 sc1\n\t"                \
      "global_load_dwordx4 %2, %4, off offset:128 sc0 sc1\n\t"               \
      "global_load_dwordx4 %3, %4, off offset:144 sc0 sc1"                   \
      : "=v"(p0.f), "=v"(p1.f), "=v"(p2.f), "=v"(p3.f)                       \
      : "v"(hb)                                                              \
      : "memory")

#define CHECK(P)                                                             \
  do {                                                                       \
    bad |= (P.u[0] ^ st) & 15u;                                              \
    bad |= (P.u[1] ^ st) & 15u;                                              \
    bad |= (P.u[2] ^ st) & 15u;                                              \
    bad |= (P.u[3] ^ st) & 15u;                                              \
  } while (0)

// 8 MFMAs over the 8 N-tiles with A-operand AV and k-frag c
#define MM8(AV, WU, c)                                                       \
  a0 = MFMA16(AV, WU[0][c], a0);                                             \
  a1 = MFMA16(AV, WU[1][c], a1);                                             \
  a2 = MFMA16(AV, WU[2][c], a2);                                             \
  a3 = MFMA16(AV, WU[3][c], a3);                                             \
  a4 = MFMA16(AV, WU[4][c], a4);                                             \
  a5 = MFMA16(AV, WU[5][c], a5);                                             \
  a6 = MFMA16(AV, WU[6][c], a6);                                             \
  a7 = MFMA16(AV, WU[7][c], a7);

// unpack chunk c (8 u32 -> hi/lo bf16x8) and run 16 MFMAs
#define HU(PA, PB, c)                                                        \
  do {                                                                       \
    pv128 hi_, lo_;                                                          \
    hi_.u[0] = (PA.u[0] >> 16) | (PA.u[1] & 0xFFFF0000u);                    \
    hi_.u[1] = (PA.u[2] >> 16) | (PA.u[3] & 0xFFFF0000u);                    \
    hi_.u[2] = (PB.u[0] >> 16) | (PB.u[1] & 0xFFFF0000u);                    \
    hi_.u[3] = (PB.u[2] >> 16) | (PB.u[3] & 0xFFFF0000u);                    \
    lo_.u[0] = (PA.u[0] & 0xFFF0u) | ((PA.u[1] & 0xFFF0u) << 16);            \
    lo_.u[1] = (PA.u[2] & 0xFFF0u) | ((PA.u[3] & 0xFFF0u) << 16);            \
    lo_.u[2] = (PB.u[0] & 0xFFF0u) | ((PB.u[1] & 0xFFF0u) << 16);            \
    lo_.u[3] = (PB.u[2] & 0xFFF0u) | ((PB.u[3] & 0xFFF0u) << 16);            \
    MM8(hi_.h, Ur, c)                                                        \
    MM8(lo_.h, Ur, c)                                                        \
  } while (0)

__launch_bounds__(512, 1)
__global__ void lstm_fused(const bf16_t* __restrict__ xb,   // [B][T][D] bf16
                           const bf16_t* __restrict__ Wt,   // [2048][512] bf16
                           const bf16_t* __restrict__ Ut,   // [2048][512] bf16
                           const float* __restrict__ bias,  // [2048]
                           float* __restrict__ out,         // [B][T][H] fp32
                           uint32_t* __restrict__ hbuf) {   // [2 par][B][H] u32
  __shared__ float EX[8][4][16][36];  // [wave][gate][row][col pad36]

  const int blk  = blockIdx.x;
  const int g    = blk >> 4;
  const int s    = blk & 15;
  const int wv   = threadIdx.x >> 6;   // 0..7
  const int lane = threadIdx.x & 63;
  const int l15  = lane & 15;
  const int l4   = lane >> 4;
  const int b0   = g * 16;
  const int hc0  = s * 32;
  const int k0   = wv * 64;            // this wave's k-chunk

  // ---- weights into registers (MFMA B-frag order), 8 N-tiles x 2 k-frags ----
  bf16x8 Wr[8][2], Ur[8][2];
#pragma unroll
  for (int n = 0; n < 8; ++n) {
    int zc = (n >> 1) * Hdim + hc0 + (n & 1) * 16 + l15;
    const bf16_t* wsrc = Wt + (size_t)zc * Ddim + k0 + l4 * 8;
    const bf16_t* usrc = Ut + (size_t)zc * Ddim + k0 + l4 * 8;
#pragma unroll
    for (int c = 0; c < 2; ++c) {
      Wr[n][c] = *(const bf16x8*)(wsrc + c * 32);
      Ur[n][c] = *(const bf16x8*)(usrc + c * 32);
    }
  }

  // update-thread mapping: one h element per thread
  const int urow = threadIdx.x >> 5;   // 0..15
  const int ucol = threadIdx.x & 31;   // 0..31
  float b4[4];
#pragma unroll
  for (int G = 0; G < 4; ++G) b4[G] = bias[G * Hdim + hc0 + ucol];
  float cstate = 0.f;
  float* outp = out + (size_t)(b0 + urow) * Tdim * Hdim + hc0 + ucol;
  uint32_t* hpub = hbuf + (size_t)(b0 + urow) * Hdim + hc0 + ucol;
  const uint32_t* hrd = hbuf + (size_t)(b0 + l15) * Hdim + k0 + l4 * 8;
  const bf16_t* xrow = xb + (size_t)(b0 + l15) * Tdim * Ddim + k0 + l4 * 8;

  // ---- prologue: x(0) into regs (plain loads) ----
  pv128 xr0, xr1;
  asm volatile(
      "global_load_dwordx4 %0, %2, off\n\t"
      "global_load_dwordx4 %1, %2, off offset:64\n\t"
      "s_waitcnt vmcnt(0)"
      : "=v"(xr0.f), "=v"(xr1.f)
      : "v"(xrow) : "memory");
  __builtin_amdgcn_sched_barrier(0);

  bool dead = false;

  for (int t = 0; t < Tdim; ++t) {
    pv128 p0, p1, p2, p3;
    const uint32_t st = (uint32_t)t & 15u;  // stamp on h_{t-1}
    const uint32_t* hb = hrd + (((t - 1) & 1) ? BH : 0);

    // [P] issue stamped h polls; they fly during x@W
    if (t > 0 && !dead) {
      ISSUE_POLL();
      __builtin_amdgcn_sched_barrier(0);
    }

    // [A] x_t @ W (registers only)
    f32x4 a0 = {0, 0, 0, 0}, a1 = {0, 0, 0, 0}, a2 = {0, 0, 0, 0}, a3 = {0, 0, 0, 0};
    f32x4 a4 = {0, 0, 0, 0}, a5 = {0, 0, 0, 0}, a6 = {0, 0, 0, 0}, a7 = {0, 0, 0, 0};
    MM8(xr0.h, Wr, 0)
    MM8(xr1.h, Wr, 1)

    if (t > 0) {
      // [C] poll until all 16 words carry stamp t
      if (!dead) {
        int guard = 0;
        for (;;) {
          asm volatile("s_waitcnt vmcnt(0)" ::: "memory");
          __builtin_amdgcn_sched_barrier(0);
          uint32_t bad = 0;
          CHECK(p0); CHECK(p1); CHECK(p2); CHECK(p3);
          if (__all(bad == 0)) break;
          if (++guard > 200000) { dead = true; break; }
          ISSUE_POLL();
          __builtin_amdgcn_sched_barrier(0);
        }
      } else {
        p0.u = p1.u = p2.u = p3.u = (u32x4)(0u);
      }
      // [U] unpack + h @ U (hi + lo)
      HU(p0, p1, 0);
      HU(p2, p3, 1);
    }

    // [D] prefetch x(t+1) (plain loads)
    {
      const bf16_t* xp = xrow + (size_t)((t + 1 < Tdim) ? t + 1 : Tdim - 1) * Ddim;
      asm volatile(
          "global_load_dwordx4 %0, %2, off\n\t"
          "global_load_dwordx4 %1, %2, off offset:64"
          : "=v"(xr0.f), "=v"(xr1.f)
          : "v"(xp) : "memory");
    }

    // [G] k-partial z -> LDS
#pragma unroll
    for (int n = 0; n < 8; ++n) {
      f32x4 av = (n == 0) ? a0 : (n == 1) ? a1 : (n == 2) ? a2 : (n == 3) ? a3
               : (n == 4) ? a4 : (n == 5) ? a5 : (n == 6) ? a6 : a7;
#pragma unroll
      for (int r = 0; r < 4; ++r)
        EX[wv][n >> 1][l4 * 4 + r][(n & 1) * 16 + l15] = av[r];
    }
    __syncthreads();

    // [H] per-element update + direct stamped publish
    float z0 = b4[0], z1 = b4[1], z2 = b4[2], z3 = b4[3];
#pragma unroll
    for (int w = 0; w < 8; ++w) {
      z0 += EX[w][0][urow][ucol];
      z1 += EX[w][1][urow][ucol];
      z2 += EX[w][2][urow][ucol];
      z3 += EX[w][3][urow][ucol];
    }
    float ig = sigmoid_f(z0), fg = sigmoid_f(z1);
    float ct = tanh_f(z2), og = sigmoid_f(z3);
    float cn = tanh_f(fg * cstate + ig * ct);  // module carries ACTIVATED cell
    cstate = cn;
    float h = og * cn;

    bu16 hh; hh.b = (bf16_t)h;
    bu16 hl; hl.b = (bf16_t)(h - (float)hh.b);
    uint32_t pubw = ((uint32_t)hh.u << 16) | ((uint32_t)hl.u & 0xFFF0u) |
                    ((uint32_t)(t + 1) & 15u);
    uint32_t* dst = hpub + ((t & 1) ? BH : 0);
    asm volatile("global_store_dword %0, %1, off sc0 sc1" ::"v"(dst), "v"(pubw)
                 : "memory");
    __builtin_nontemporal_store(h, outp + (size_t)t * Hdim);

    __syncthreads();  // EX WAR protection (keeps waves in lockstep)

    // [J] drain x prefetch (and stores) before next [A]
    asm volatile("s_waitcnt vmcnt(0)" ::: "memory");
    __builtin_amdgcn_sched_barrier(0);
  }
}

extern "C" void kernel_launch(void* const* d_in, const int* in_sizes, int n_in,
                              void* d_out, int out_size, void* d_ws, size_t ws_size,
                              hipStream_t stream) {
  const float* x    = (const float*)d_in[0];
  const float* W    = (const float*)d_in[1];
  const float* U    = (const float*)d_in[2];
  const float* bias = (const float*)d_in[3];
  float* out = (float*)d_out;

  unsigned char* ws = (unsigned char*)d_ws;
  // layout: hbuf 256 KB (memset each call) | Wt 2 MB | Ut 2 MB | xb 32 MB
  uint32_t* hbuf = (uint32_t*)ws;
  bf16_t* Wt = (bf16_t*)(ws + 262144);
  bf16_t* Ut = Wt + (size_t)G4H * Ddim;
  bf16_t* xb = Ut + (size_t)G4H * Ddim;

  hipMemsetAsync(hbuf, 0, 262144, stream);

  cast_bf16<<<(Bdim * Tdim * Ddim) / 2048, 256, 0, stream>>>(x, xb);

  dim3 tgrid(G4H / 64, Ddim / 64);
  transpose_bf16_512x2048<<<tgrid, 256, 0, stream>>>(W, Wt);
  transpose_bf16_512x2048<<<tgrid, 256, 0, stream>>>(U, Ut);

  lstm_fused<<<NG * NS, 512, 0, stream>>>(xb, Wt, Ut, bias, out, hbuf);
}